// Round 6
// baseline (460.907 us; speedup 1.0000x reference)
//
#include <hip/hip_runtime.h>
#include <hip/hip_bf16.h>

// Sizes
#define B_ 256
#define D_ 3072
#define H_ 256
#define OPT_ 32
#define OD_ 98304       // OPT_*D_
#define NL_ 4

typedef __attribute__((ext_vector_type(8))) short short8;
typedef __attribute__((ext_vector_type(4))) float f32x4;

__device__ __forceinline__ unsigned short f2bf(float f) {
    unsigned int u = __float_as_uint(f);
    unsigned int r = (u + 0x7FFFu + ((u >> 16) & 1u)) >> 16;
    return (unsigned short)r;
}

// ---------------------------------------------------------------------------
// init: cur = 0, rx = -x, zpart = 0.  Grid 512 blocks, grid-stride.
__global__ __launch_bounds__(256) void init_kernel(const float* __restrict__ x,
                                                   float* __restrict__ cur,
                                                   float* __restrict__ rx,
                                                   float* __restrict__ zpart) {
    int gid0 = blockIdx.x * 256 + threadIdx.x;   // 131072 threads
    for (int g = gid0; g < B_ * D_; g += 131072) {
        cur[g] = 0.f;
        rx[g] = -x[g];
    }
    for (int g = gid0; g < 16 * B_ * H_; g += 131072) zpart[g] = 0.f;
}

// ---------------------------------------------------------------------------
// gemm1: zpart[ks][b][h] = sum_{d in 192-slice ks} cur[b][d] * Wb[d][h]
// grid 512 blocks (16 kslices x 32 bgroups of 8 b), 256 threads (= h)
__global__ __launch_bounds__(256) void gemm1_kernel(const float* __restrict__ cur,
                                                    const float* __restrict__ Wb,
                                                    float* __restrict__ zpart) {
    int t = threadIdx.x;
    int ks = blockIdx.x >> 5;     // 0..15
    int bg = blockIdx.x & 31;     // 0..31
    const float* wp = Wb + (size_t)ks * 192 * H_ + t;
    const float* cp = cur + (size_t)(bg * 8) * D_ + ks * 192;
    float acc[8] = {0.f, 0.f, 0.f, 0.f, 0.f, 0.f, 0.f, 0.f};
#pragma unroll 4
    for (int dd = 0; dd < 192; ++dd) {
        float w = wp[(size_t)dd * H_];
#pragma unroll
        for (int g = 0; g < 8; ++g) acc[g] += cp[(size_t)g * D_ + dd] * w;
    }
#pragma unroll
    for (int g = 0; g < 8; ++g)
        zpart[ks * (B_ * H_) + (bg * 8 + g) * H_ + t] = acc[g];
}

// ---------------------------------------------------------------------------
// E: base = relu(sum_ks zpart + bb). Writes bf16 staging image + f32 basef.
__global__ __launch_bounds__(256) void e_kernel(const float* __restrict__ zpart,
                                                const float* __restrict__ bb,
                                                unsigned char* __restrict__ base_ready,
                                                float* __restrict__ basef) {
    int m = blockIdx.x, k = threadIdx.x;
    float z = bb[k];
#pragma unroll
    for (int ks = 0; ks < 16; ++ks) z += zpart[ks * (B_ * H_) + m * H_ + k];
    z = z > 0.f ? z : 0.f;
    *(unsigned short*)(base_ready + (k >> 5) * 20480 + m * 80 + (k & 31) * 2) = f2bf(z);
    basef[m * H_ + k] = z;
}

// ---------------------------------------------------------------------------
// G2: fused GEMM (256x98304, K=256, bf16 MFMA) + squared-loss partials.
// T3/T4 schedule: A staged by global_load_lds DMA (1 step ahead, L2-hot);
// W fp32 loads in TWO register sets issued 2 steps ahead (HBM stream);
// raw s_barrier + counted "s_waitcnt vmcnt(8)" so the 8 in-flight W loads
// survive the barrier (__syncthreads would drain vmcnt(0) = the m97 stall).
__global__ __launch_bounds__(512, 4) void g2_kernel(const unsigned char* __restrict__ base_ready,
                                                    const float* __restrict__ Wo,    // [256][98304] layer slice
                                                    const float* __restrict__ biasL, // [32*3072]
                                                    const float* __restrict__ boL,   // [98304]
                                                    const float* __restrict__ rx,    // [256*3072]
                                                    float* __restrict__ partial) {
    __shared__ __align__(16) unsigned char ldsA[2][20480];  // [m][32k bf16 + pad]
    __shared__ __align__(16) unsigned char ldsW[2][10240];  // [n][32k bf16 + pad]

    int t = threadIdx.x;
    int lane = t & 63, wv = t >> 6;
    int bx = blockIdx.x;
    int ncol0 = bx * 128;
    int o = bx / 24;                 // 24 blocks per option
    int dbase = (bx % 24) * 128;

    int wm = wv >> 1, wn = wv & 1;
    int lrow = lane & 15, lk = lane >> 4;
    int nW = t & 127, kq = t >> 7;   // W staging role: kq in 0..3

    f32x4 acc[4][4];
#pragma unroll
    for (int mi = 0; mi < 4; ++mi)
#pragma unroll
        for (int ni = 0; ni < 4; ++ni) acc[mi][ni] = 0.f;

    float wfX[8], wfY[8];

    // A image for step S -> ldsA[BUF] via direct-to-LDS DMA (3 wave-uniform issues)
#define DMA_A(S, BUF) {                                                                  \
    const unsigned char* gA = base_ready + (S) * 20480;                                  \
    __builtin_amdgcn_global_load_lds(                                                    \
        (const __attribute__((address_space(1))) unsigned int*)(gA + t * 16),            \
        (__attribute__((address_space(3))) unsigned int*)(&ldsA[BUF][0] + wv * 1024),    \
        16, 0, 0);                                                                       \
    __builtin_amdgcn_global_load_lds(                                                    \
        (const __attribute__((address_space(1))) unsigned int*)(gA + 8192 + t * 16),     \
        (__attribute__((address_space(3))) unsigned int*)(&ldsA[BUF][0] + 8192 + wv * 1024), \
        16, 0, 0);                                                                       \
    if (wv < 4)                                                                          \
        __builtin_amdgcn_global_load_lds(                                                \
            (const __attribute__((address_space(1))) unsigned int*)(gA + 16384 + t * 16),\
            (__attribute__((address_space(3))) unsigned int*)(&ldsA[BUF][0] + 16384 + wv * 1024), \
            16, 0, 0); }

#define LOADW_(S, WF) {                                                                  \
    const float* gp0 = Wo + (size_t)((S) * 32 + kq * 4) * OD_ + ncol0 + nW;              \
    WF[0] = gp0[0]; WF[1] = gp0[OD_]; WF[2] = gp0[2 * OD_]; WF[3] = gp0[3 * OD_];        \
    const float* gp1 = gp0 + (size_t)16 * OD_;                                           \
    WF[4] = gp1[0]; WF[5] = gp1[OD_]; WF[6] = gp1[2 * OD_]; WF[7] = gp1[3 * OD_]; }

#define WRITEW_(BUF, WF) {                                                               \
    uint2 pk0, pk1;                                                                      \
    pk0.x = (unsigned)f2bf(WF[0]) | ((unsigned)f2bf(WF[1]) << 16);                       \
    pk0.y = (unsigned)f2bf(WF[2]) | ((unsigned)f2bf(WF[3]) << 16);                       \
    *(uint2*)(ldsW[BUF] + nW * 80 + kq * 8) = pk0;                                       \
    pk1.x = (unsigned)f2bf(WF[4]) | ((unsigned)f2bf(WF[5]) << 16);                       \
    pk1.y = (unsigned)f2bf(WF[6]) | ((unsigned)f2bf(WF[7]) << 16);                       \
    *(uint2*)(ldsW[BUF] + nW * 80 + 32 + kq * 8) = pk1; }

    // prologue: A(0) DMA; W(0)->X, W(1)->Y in flight; write W(0) (auto-waits X+A0)
    DMA_A(0, 0);
    LOADW_(0, wfX);
    LOADW_(1, wfY);
    WRITEW_(0, wfX);
    asm volatile("s_waitcnt lgkmcnt(0)" ::: "memory");
    __builtin_amdgcn_s_barrier();
    __builtin_amdgcn_sched_barrier(0);

#pragma unroll
    for (int s = 0; s < 8; ++s) {
        int cur = s & 1;
        // issue next A (1 step ahead) and next-next W (2 steps ahead)
        if (s < 7) DMA_A(s + 1, cur ^ 1);
        if (s < 6) {
            if ((s & 1) == 0) { LOADW_(s + 2, wfX); }
            else              { LOADW_(s + 2, wfY); }
        }
        // compute step s
        short8 bfr[4];
#pragma unroll
        for (int ni = 0; ni < 4; ++ni) {
            int nn = wn * 64 + ni * 16 + lrow;
            bfr[ni] = *(const short8*)(ldsW[cur] + nn * 80 + lk * 16);
        }
#pragma unroll
        for (int mi = 0; mi < 4; ++mi) {
            int row = wm * 64 + mi * 16 + lrow;
            short8 af = *(const short8*)(ldsA[cur] + row * 80 + lk * 16);
#pragma unroll
            for (int ni = 0; ni < 4; ++ni)
                acc[mi][ni] = __builtin_amdgcn_mfma_f32_16x16x32_bf16(af, bfr[ni], acc[mi][ni], 0, 0, 0);
        }
        // write step s+1's W (auto-waits its 8 loads, issued 2 steps ago)
        if (s < 7) {
            if ((s & 1) == 0) { WRITEW_(cur ^ 1, wfY); }
            else              { WRITEW_(cur ^ 1, wfX); }
            if (s < 6) asm volatile("s_waitcnt vmcnt(8) lgkmcnt(0)" ::: "memory");  // drain A(s+1); keep W(s+2)
            else       asm volatile("s_waitcnt vmcnt(0) lgkmcnt(0)" ::: "memory");  // last: drain A(7)
            __builtin_amdgcn_s_barrier();
            __builtin_amdgcn_sched_barrier(0);
        }
    }

#undef DMA_A
#undef LOADW_
#undef WRITEW_

    // epilogue: loss partials
    float q[4];
#pragma unroll
    for (int ni = 0; ni < 4; ++ni) {
        int dcol = dbase + wn * 64 + ni * 16 + lrow;
        q[ni] = biasL[o * D_ + dcol] + boL[o * D_ + dcol];
    }
    float ssum[4][4];
#pragma unroll
    for (int mi = 0; mi < 4; ++mi)
#pragma unroll
        for (int r = 0; r < 4; ++r) ssum[mi][r] = 0.f;

#pragma unroll
    for (int mi = 0; mi < 4; ++mi) {
#pragma unroll
        for (int ni = 0; ni < 4; ++ni) {
            int dcol = dbase + wn * 64 + ni * 16 + lrow;
#pragma unroll
            for (int r = 0; r < 4; ++r) {
                int rowm = wm * 64 + mi * 16 + lk * 4 + r;
                float tv = acc[mi][ni][r] + rx[rowm * D_ + dcol] + q[ni];
                ssum[mi][r] += tv * tv;
            }
        }
    }
#pragma unroll
    for (int mi = 0; mi < 4; ++mi)
#pragma unroll
        for (int r = 0; r < 4; ++r) {
            float v = ssum[mi][r];
            v += __shfl_xor(v, 1);
            v += __shfl_xor(v, 2);
            v += __shfl_xor(v, 4);
            v += __shfl_xor(v, 8);
            if (lrow == 0) {
                int rowm = wm * 64 + mi * 16 + lk * 4 + r;
                partial[(rowm * OPT_ + o) * 48 + (bx % 24) * 2 + wn] = v;
            }
        }
}

// ---------------------------------------------------------------------------
// C: per-b argmin over 32 options (tie-break lowest index = jnp.argmin).
__global__ __launch_bounds__(256) void c_kernel(const float* __restrict__ partial,
                                                int* __restrict__ idxbuf,
                                                float* __restrict__ enc, int layer) {
    __shared__ float ls[32];
    int b = blockIdx.x, t = threadIdx.x;
    int oo = t >> 3, j8 = t & 7;
    const float* pp = partial + (b * OPT_ + oo) * 48;
    float v = 0.f;
#pragma unroll
    for (int j = 0; j < 6; ++j) v += pp[j8 + 8 * j];
    v += __shfl_xor(v, 1);
    v += __shfl_xor(v, 2);
    v += __shfl_xor(v, 4);
    if (j8 == 0) ls[oo] = v;
    __syncthreads();
    if (t < 32) {
        float mv = ls[t];
        int mi = t;
#pragma unroll
        for (int m = 16; m >= 1; m >>= 1) {
            float ov = __shfl_xor(mv, m);
            int oi = __shfl_xor(mi, m);
            if (ov < mv || (ov == mv && oi < mi)) { mv = ov; mi = oi; }
        }
        if (t == 0) {
            idxbuf[b] = mi;
            enc[b * NL_ + layer] = (float)mi;
        }
    }
}

// ---------------------------------------------------------------------------
// D: recompute selected option. Bucketing is FUSED (deterministic rank-scan
// from idxbuf, no atomics -> identical work partition in every block; removes
// the single-block bucket kernel + its launch gap). grid (32 x 12) = 384
// blocks, each handles work items j = bx, bx+32, ... (compact, no empties).
__global__ __launch_bounds__(256) void d_kernel(const int* __restrict__ idxbuf,
                                                const float* __restrict__ basef,
                                                const float* __restrict__ Wo,
                                                const float* __restrict__ boL,
                                                const float* __restrict__ biasL,
                                                const float* __restrict__ x,
                                                float* __restrict__ cur,
                                                float* __restrict__ rx) {
    __shared__ int sidx[256];
    __shared__ int scnt[32];
    __shared__ int snch[32];
    __shared__ int chunk_b[8];
    __shared__ float basL[8][256];
    int t = threadIdx.x;
    int dt = blockIdx.y;

    sidx[t] = idxbuf[t];
    __syncthreads();
    if (t < 32) {
        int c = 0;
        for (int b = 0; b < 256; ++b) c += (sidx[b] == t);
        scnt[t] = c;
        snch[t] = (c + 7) >> 3;
    }
    __syncthreads();
    // my rank among ascending b with same option (deterministic)
    int myo = sidx[t];
    int myrank = 0;
    for (int b = 0; b < t; ++b) myrank += (sidx[b] == myo);

    for (int j = blockIdx.x; ; j += 32) {
        // decode work item j -> (o, chunk) via prefix walk (uniform)
        int o = -1, ch = 0, pre = 0;
        for (int oo = 0; oo < 32; ++oo) {
            int n = snch[oo];
            if (j < pre + n) { o = oo; ch = j - pre; break; }
            pre += n;
        }
        if (o < 0) break;
        int cnt = scnt[o];
        int c0 = ch * 8;
        int rem = cnt - c0;
        if (rem > 8) rem = 8;

        __syncthreads();   // previous item's basL readers done before reuse
        if (myo == o && myrank >= c0 && myrank < c0 + 8) chunk_b[myrank - c0] = t;
        __syncthreads();

        int bidx[8];
#pragma unroll
        for (int g = 0; g < 8; ++g) bidx[g] = chunk_b[(g < rem) ? g : (rem - 1)];
#pragma unroll
        for (int g = 0; g < 8; ++g) basL[g][t] = basef[bidx[g] * H_ + t];
        __syncthreads();

        int d = dt * 256 + t;
        const float* wp = Wo + (size_t)o * D_ + d;
        size_t nn = (size_t)o * D_ + d;
        float bov = boL[nn];
        float biv = biasL[nn];

        float acc[8] = {0.f, 0.f, 0.f, 0.f, 0.f, 0.f, 0.f, 0.f};
        for (int k0 = 0; k0 < 256; k0 += 8) {
            float w[8];
#pragma unroll
            for (int u = 0; u < 8; ++u) w[u] = wp[(size_t)(k0 + u) * OD_];
#pragma unroll
            for (int h = 0; h < 2; ++h) {
                int kb = k0 + h * 4;
                f32x4 bv[8];
#pragma unroll
                for (int g = 0; g < 8; ++g) bv[g] = *(const f32x4*)&basL[g][kb];
#pragma unroll
                for (int u = 0; u < 4; ++u) {
                    float wu = w[h * 4 + u];
#pragma unroll
                    for (int g = 0; g < 8; ++g) acc[g] += bv[g][u] * wu;   // k ascending
                }
            }
        }
#pragma unroll
        for (int g = 0; g < 8; ++g) {
            if (g < rem) {
                int b = bidx[g];
                float outv = cur[b * D_ + d] + acc[g] + bov + biv;
                cur[b * D_ + d] = outv;
                rx[b * D_ + d] = outv - x[b * D_ + d];
            }
        }
    }
}

// ---------------------------------------------------------------------------
extern "C" void kernel_launch(void* const* d_in, const int* in_sizes, int n_in,
                              void* d_out, int out_size, void* d_ws, size_t ws_size,
                              hipStream_t stream) {
    const float* x    = (const float*)d_in[0];  // [256][3072]
    const float* Wb   = (const float*)d_in[1];  // [3072][256]
    const float* bb   = (const float*)d_in[2];  // [256]
    const float* Wo   = (const float*)d_in[3];  // [4][256][98304]
    const float* bo   = (const float*)d_in[4];  // [4][98304]
    const float* bias = (const float*)d_in[5];  // [4][32][3072]

    float* out = (float*)d_out;
    float* enc = out;            // [256][4] (indices as float)
    float* cur = out + 1024;     // [256][3072] reconstruction

    float* ws = (float*)d_ws;
    float* zpart   = ws;                          // 16*256*256 = 1048576
    float* partial = ws + 1048576;                // 256*32*48  = 393216
    float* rx      = ws + 1441792;                // 256*3072   = 786432
    float* basef   = ws + 2228224;                // 256*256    = 65536
    unsigned char* base_ready = (unsigned char*)(ws + 2293760);  // 163840 B
    int* idxbuf    = (int*)(ws + 2334720);        // 256 ints

    init_kernel<<<512, 256, 0, stream>>>(x, cur, rx, zpart);

    for (int i = 0; i < NL_; ++i) {
        const float* WoL   = Wo + (size_t)i * H_ * OD_;
        const float* boLp  = bo + (size_t)i * OD_;
        const float* biasL = bias + (size_t)i * OD_;
        if (i > 0) gemm1_kernel<<<512, 256, 0, stream>>>(cur, Wb, zpart);
        e_kernel<<<256, 256, 0, stream>>>(zpart, bb, base_ready, basef);
        g2_kernel<<<768, 512, 0, stream>>>(base_ready, WoL, biasL, boLp, rx, partial);
        c_kernel<<<256, 256, 0, stream>>>(partial, idxbuf, enc, i);
        d_kernel<<<dim3(32, 12), 256, 0, stream>>>(idxbuf, basef, WoL, boLp, biasL, x, cur, rx);
    }
}

// Round 7
// 390.652 us; speedup vs baseline: 1.1798x; 1.1798x over previous
//
#include <hip/hip_runtime.h>
#include <hip/hip_bf16.h>

// Sizes
#define B_ 256
#define D_ 3072
#define H_ 256
#define OPT_ 32
#define OD_ 98304       // OPT_*D_
#define NL_ 4

typedef __attribute__((ext_vector_type(8))) short short8;
typedef __attribute__((ext_vector_type(4))) float f32x4;

__device__ __forceinline__ unsigned short f2bf(float f) {
    unsigned int u = __float_as_uint(f);
    unsigned int r = (u + 0x7FFFu + ((u >> 16) & 1u)) >> 16;
    return (unsigned short)r;
}

// ---------------------------------------------------------------------------
// init: cur = 0, rx = -x, zpart = 0.  Grid 512 blocks, grid-stride.
__global__ __launch_bounds__(256) void init_kernel(const float* __restrict__ x,
                                                   float* __restrict__ cur,
                                                   float* __restrict__ rx,
                                                   float* __restrict__ zpart) {
    int gid0 = blockIdx.x * 256 + threadIdx.x;   // 131072 threads
    for (int g = gid0; g < B_ * D_; g += 131072) {
        cur[g] = 0.f;
        rx[g] = -x[g];
    }
    for (int g = gid0; g < 16 * B_ * H_; g += 131072) zpart[g] = 0.f;
}

// ---------------------------------------------------------------------------
// gemm1: zpart[ks][b][h] = sum_{d in 192-slice ks} cur[b][d] * Wb[d][h]
// grid 512 blocks (16 kslices x 32 bgroups of 8 b), 256 threads (= h)
__global__ __launch_bounds__(256) void gemm1_kernel(const float* __restrict__ cur,
                                                    const float* __restrict__ Wb,
                                                    float* __restrict__ zpart) {
    int t = threadIdx.x;
    int ks = blockIdx.x >> 5;     // 0..15
    int bg = blockIdx.x & 31;     // 0..31
    const float* wp = Wb + (size_t)ks * 192 * H_ + t;
    const float* cp = cur + (size_t)(bg * 8) * D_ + ks * 192;
    float acc[8] = {0.f, 0.f, 0.f, 0.f, 0.f, 0.f, 0.f, 0.f};
#pragma unroll 4
    for (int dd = 0; dd < 192; ++dd) {
        float w = wp[(size_t)dd * H_];
#pragma unroll
        for (int g = 0; g < 8; ++g) acc[g] += cp[(size_t)g * D_ + dd] * w;
    }
#pragma unroll
    for (int g = 0; g < 8; ++g)
        zpart[ks * (B_ * H_) + (bg * 8 + g) * H_ + t] = acc[g];
}

// ---------------------------------------------------------------------------
// E: base = relu(sum_ks zpart + bb). Writes bf16 staging image + f32 basef.
__global__ __launch_bounds__(256) void e_kernel(const float* __restrict__ zpart,
                                                const float* __restrict__ bb,
                                                unsigned char* __restrict__ base_ready,
                                                float* __restrict__ basef) {
    int m = blockIdx.x, k = threadIdx.x;
    float z = bb[k];
#pragma unroll
    for (int ks = 0; ks < 16; ++ks) z += zpart[ks * (B_ * H_) + m * H_ + k];
    z = z > 0.f ? z : 0.f;
    *(unsigned short*)(base_ready + (k >> 5) * 20480 + m * 80 + (k & 31) * 2) = f2bf(z);
    basef[m * H_ + k] = z;
}

// ---------------------------------------------------------------------------
// G2: fused GEMM (256x98304, K=256, bf16 MFMA) + squared-loss partials.
// T3/T4 schedule: A staged by global_load_lds DMA (1 step ahead, L2-hot);
// W fp32 loads in TWO register sets (X/Y) issued 2 steps ahead (HBM stream);
// raw s_barrier + counted "s_waitcnt vmcnt(8)" keeps the 8 in-flight W loads
// alive across each barrier. NO sched_barrier(0) (m141: order-pinning
// regression) and only unroll-2 (parity for X/Y) -- compiler schedules freely.
__global__ __launch_bounds__(512, 4) void g2_kernel(const unsigned char* __restrict__ base_ready,
                                                    const float* __restrict__ Wo,    // [256][98304] layer slice
                                                    const float* __restrict__ biasL, // [32*3072]
                                                    const float* __restrict__ boL,   // [98304]
                                                    const float* __restrict__ rx,    // [256*3072]
                                                    float* __restrict__ partial) {
    __shared__ __align__(16) unsigned char ldsA[2][20480];  // [m][32k bf16 + pad]
    __shared__ __align__(16) unsigned char ldsW[2][10240];  // [n][32k bf16 + pad]

    int t = threadIdx.x;
    int lane = t & 63, wv = t >> 6;
    int bx = blockIdx.x;
    int ncol0 = bx * 128;
    int o = bx / 24;                 // 24 blocks per option
    int dbase = (bx % 24) * 128;

    int wm = wv >> 1, wn = wv & 1;
    int lrow = lane & 15, lk = lane >> 4;
    int nW = t & 127, kq = t >> 7;   // W staging role: kq in 0..3

    f32x4 acc[4][4];
#pragma unroll
    for (int mi = 0; mi < 4; ++mi)
#pragma unroll
        for (int ni = 0; ni < 4; ++ni) acc[mi][ni] = 0.f;

    float wfX[8], wfY[8];

    // A image for step S -> ldsA[BUF] via direct-to-LDS DMA (wave-uniform dest)
#define DMA_A(S, BUF) {                                                                  \
    const unsigned char* gA = base_ready + (S) * 20480;                                  \
    __builtin_amdgcn_global_load_lds(                                                    \
        (const __attribute__((address_space(1))) unsigned int*)(gA + t * 16),            \
        (__attribute__((address_space(3))) unsigned int*)(&ldsA[BUF][0] + wv * 1024),    \
        16, 0, 0);                                                                       \
    __builtin_amdgcn_global_load_lds(                                                    \
        (const __attribute__((address_space(1))) unsigned int*)(gA + 8192 + t * 16),     \
        (__attribute__((address_space(3))) unsigned int*)(&ldsA[BUF][0] + 8192 + wv * 1024), \
        16, 0, 0);                                                                       \
    if (wv < 4)                                                                          \
        __builtin_amdgcn_global_load_lds(                                                \
            (const __attribute__((address_space(1))) unsigned int*)(gA + 16384 + t * 16),\
            (__attribute__((address_space(3))) unsigned int*)(&ldsA[BUF][0] + 16384 + wv * 1024), \
            16, 0, 0); }

#define LOADW_(S, WF) {                                                                  \
    const float* gp0 = Wo + (size_t)((S) * 32 + kq * 4) * OD_ + ncol0 + nW;              \
    WF[0] = gp0[0]; WF[1] = gp0[OD_]; WF[2] = gp0[2 * OD_]; WF[3] = gp0[3 * OD_];        \
    const float* gp1 = gp0 + (size_t)16 * OD_;                                           \
    WF[4] = gp1[0]; WF[5] = gp1[OD_]; WF[6] = gp1[2 * OD_]; WF[7] = gp1[3 * OD_]; }

#define WRITEW_(BUF, WF) {                                                               \
    uint2 pk0, pk1;                                                                      \
    pk0.x = (unsigned)f2bf(WF[0]) | ((unsigned)f2bf(WF[1]) << 16);                       \
    pk0.y = (unsigned)f2bf(WF[2]) | ((unsigned)f2bf(WF[3]) << 16);                       \
    *(uint2*)(ldsW[BUF] + nW * 80 + kq * 8) = pk0;                                       \
    pk1.x = (unsigned)f2bf(WF[4]) | ((unsigned)f2bf(WF[5]) << 16);                       \
    pk1.y = (unsigned)f2bf(WF[6]) | ((unsigned)f2bf(WF[7]) << 16);                       \
    *(uint2*)(ldsW[BUF] + nW * 80 + 32 + kq * 8) = pk1; }

    // prologue: A(0) DMA; W(0)->X, W(1)->Y in flight; write W(0)
    DMA_A(0, 0);
    LOADW_(0, wfX);
    LOADW_(1, wfY);
    WRITEW_(0, wfX);
    asm volatile("s_waitcnt lgkmcnt(0)" ::: "memory");
    __builtin_amdgcn_s_barrier();

#pragma unroll 2
    for (int s = 0; s < 8; ++s) {
        int cur = s & 1;
        // issue next A (1 step ahead) and next-next W (2 steps ahead)
        if (s < 7) DMA_A(s + 1, cur ^ 1);
        if (s < 6) {
            if ((s & 1) == 0) { LOADW_(s + 2, wfX); }
            else              { LOADW_(s + 2, wfY); }
        }
        // compute step s
        short8 bfr[4];
#pragma unroll
        for (int ni = 0; ni < 4; ++ni) {
            int nn = wn * 64 + ni * 16 + lrow;
            bfr[ni] = *(const short8*)(ldsW[cur] + nn * 80 + lk * 16);
        }
#pragma unroll
        for (int mi = 0; mi < 4; ++mi) {
            int row = wm * 64 + mi * 16 + lrow;
            short8 af = *(const short8*)(ldsA[cur] + row * 80 + lk * 16);
#pragma unroll
            for (int ni = 0; ni < 4; ++ni)
                acc[mi][ni] = __builtin_amdgcn_mfma_f32_16x16x32_bf16(af, bfr[ni], acc[mi][ni], 0, 0, 0);
        }
        // write step s+1's W (auto-waits its 8 loads, issued 2 steps ago)
        if (s < 7) {
            if ((s & 1) == 0) { WRITEW_(cur ^ 1, wfY); }
            else              { WRITEW_(cur ^ 1, wfX); }
            if (s < 6) asm volatile("s_waitcnt vmcnt(8) lgkmcnt(0)" ::: "memory");  // drain A(s+1); keep W(s+2)
            else       asm volatile("s_waitcnt vmcnt(0) lgkmcnt(0)" ::: "memory");  // last: drain A(7)
            __builtin_amdgcn_s_barrier();
        }
    }

#undef DMA_A
#undef LOADW_
#undef WRITEW_

    // epilogue: loss partials
    float q[4];
#pragma unroll
    for (int ni = 0; ni < 4; ++ni) {
        int dcol = dbase + wn * 64 + ni * 16 + lrow;
        q[ni] = biasL[o * D_ + dcol] + boL[o * D_ + dcol];
    }
    float ssum[4][4];
#pragma unroll
    for (int mi = 0; mi < 4; ++mi)
#pragma unroll
        for (int r = 0; r < 4; ++r) ssum[mi][r] = 0.f;

#pragma unroll
    for (int mi = 0; mi < 4; ++mi) {
#pragma unroll
        for (int ni = 0; ni < 4; ++ni) {
            int dcol = dbase + wn * 64 + ni * 16 + lrow;
#pragma unroll
            for (int r = 0; r < 4; ++r) {
                int rowm = wm * 64 + mi * 16 + lk * 4 + r;
                float tv = acc[mi][ni][r] + rx[rowm * D_ + dcol] + q[ni];
                ssum[mi][r] += tv * tv;
            }
        }
    }
#pragma unroll
    for (int mi = 0; mi < 4; ++mi)
#pragma unroll
        for (int r = 0; r < 4; ++r) {
            float v = ssum[mi][r];
            v += __shfl_xor(v, 1);
            v += __shfl_xor(v, 2);
            v += __shfl_xor(v, 4);
            v += __shfl_xor(v, 8);
            if (lrow == 0) {
                int rowm = wm * 64 + mi * 16 + lk * 4 + r;
                partial[(rowm * OPT_ + o) * 48 + (bx % 24) * 2 + wn] = v;
            }
        }
}

// ---------------------------------------------------------------------------
// C: per-b argmin over 32 options (tie-break lowest index = jnp.argmin).
__global__ __launch_bounds__(256) void c_kernel(const float* __restrict__ partial,
                                                int* __restrict__ idxbuf,
                                                float* __restrict__ enc, int layer) {
    __shared__ float ls[32];
    int b = blockIdx.x, t = threadIdx.x;
    int oo = t >> 3, j8 = t & 7;
    const float* pp = partial + (b * OPT_ + oo) * 48;
    float v = 0.f;
#pragma unroll
    for (int j = 0; j < 6; ++j) v += pp[j8 + 8 * j];
    v += __shfl_xor(v, 1);
    v += __shfl_xor(v, 2);
    v += __shfl_xor(v, 4);
    if (j8 == 0) ls[oo] = v;
    __syncthreads();
    if (t < 32) {
        float mv = ls[t];
        int mi = t;
#pragma unroll
        for (int m = 16; m >= 1; m >>= 1) {
            float ov = __shfl_xor(mv, m);
            int oi = __shfl_xor(mi, m);
            if (ov < mv || (ov == mv && oi < mi)) { mv = ov; mi = oi; }
        }
        if (t == 0) {
            idxbuf[b] = mi;
            enc[b * NL_ + layer] = (float)mi;
        }
    }
}

// ---------------------------------------------------------------------------
// D: recompute selected option. Bucketing FUSED via deterministic rank-scan
// (no atomics, identical partition in every block). grid (32 x 12) = 384
// blocks, each handles work items j = bx, bx+32, ... (compact, no empties).
__global__ __launch_bounds__(256) void d_kernel(const int* __restrict__ idxbuf,
                                                const float* __restrict__ basef,
                                                const float* __restrict__ Wo,
                                                const float* __restrict__ boL,
                                                const float* __restrict__ biasL,
                                                const float* __restrict__ x,
                                                float* __restrict__ cur,
                                                float* __restrict__ rx) {
    __shared__ int sidx[256];
    __shared__ int scnt[32];
    __shared__ int snch[32];
    __shared__ int chunk_b[8];
    __shared__ float basL[8][256];
    int t = threadIdx.x;
    int dt = blockIdx.y;

    sidx[t] = idxbuf[t];
    __syncthreads();
    if (t < 32) {
        int c = 0;
        for (int b = 0; b < 256; ++b) c += (sidx[b] == t);
        scnt[t] = c;
        snch[t] = (c + 7) >> 3;
    }
    __syncthreads();
    // my rank among ascending b with same option (deterministic)
    int myo = sidx[t];
    int myrank = 0;
    for (int b = 0; b < t; ++b) myrank += (sidx[b] == myo);

    for (int j = blockIdx.x; ; j += 32) {
        // decode work item j -> (o, chunk) via prefix walk (uniform)
        int o = -1, ch = 0, pre = 0;
        for (int oo = 0; oo < 32; ++oo) {
            int n = snch[oo];
            if (j < pre + n) { o = oo; ch = j - pre; break; }
            pre += n;
        }
        if (o < 0) break;
        int cnt = scnt[o];
        int c0 = ch * 8;
        int rem = cnt - c0;
        if (rem > 8) rem = 8;

        __syncthreads();   // previous item's basL readers done before reuse
        if (myo == o && myrank >= c0 && myrank < c0 + 8) chunk_b[myrank - c0] = t;
        __syncthreads();

        int bidx[8];
#pragma unroll
        for (int g = 0; g < 8; ++g) bidx[g] = chunk_b[(g < rem) ? g : (rem - 1)];
#pragma unroll
        for (int g = 0; g < 8; ++g) basL[g][t] = basef[bidx[g] * H_ + t];
        __syncthreads();

        int d = dt * 256 + t;
        const float* wp = Wo + (size_t)o * D_ + d;
        size_t nn = (size_t)o * D_ + d;
        float bov = boL[nn];
        float biv = biasL[nn];

        float acc[8] = {0.f, 0.f, 0.f, 0.f, 0.f, 0.f, 0.f, 0.f};
        for (int k0 = 0; k0 < 256; k0 += 8) {
            float w[8];
#pragma unroll
            for (int u = 0; u < 8; ++u) w[u] = wp[(size_t)(k0 + u) * OD_];
#pragma unroll
            for (int h = 0; h < 2; ++h) {
                int kb = k0 + h * 4;
                f32x4 bv[8];
#pragma unroll
                for (int g = 0; g < 8; ++g) bv[g] = *(const f32x4*)&basL[g][kb];
#pragma unroll
                for (int u = 0; u < 4; ++u) {
                    float wu = w[h * 4 + u];
#pragma unroll
                    for (int g = 0; g < 8; ++g) acc[g] += bv[g][u] * wu;   // k ascending
                }
            }
        }
#pragma unroll
        for (int g = 0; g < 8; ++g) {
            if (g < rem) {
                int b = bidx[g];
                float outv = cur[b * D_ + d] + acc[g] + bov + biv;
                cur[b * D_ + d] = outv;
                rx[b * D_ + d] = outv - x[b * D_ + d];
            }
        }
    }
}

// ---------------------------------------------------------------------------
extern "C" void kernel_launch(void* const* d_in, const int* in_sizes, int n_in,
                              void* d_out, int out_size, void* d_ws, size_t ws_size,
                              hipStream_t stream) {
    const float* x    = (const float*)d_in[0];  // [256][3072]
    const float* Wb   = (const float*)d_in[1];  // [3072][256]
    const float* bb   = (const float*)d_in[2];  // [256]
    const float* Wo   = (const float*)d_in[3];  // [4][256][98304]
    const float* bo   = (const float*)d_in[4];  // [4][98304]
    const float* bias = (const float*)d_in[5];  // [4][32][3072]

    float* out = (float*)d_out;
    float* enc = out;            // [256][4] (indices as float)
    float* cur = out + 1024;     // [256][3072] reconstruction

    float* ws = (float*)d_ws;
    float* zpart   = ws;                          // 16*256*256 = 1048576
    float* partial = ws + 1048576;                // 256*32*48  = 393216
    float* rx      = ws + 1441792;                // 256*3072   = 786432
    float* basef   = ws + 2228224;                // 256*256    = 65536
    unsigned char* base_ready = (unsigned char*)(ws + 2293760);  // 163840 B
    int* idxbuf    = (int*)(ws + 2334720);        // 256 ints

    init_kernel<<<512, 256, 0, stream>>>(x, cur, rx, zpart);

    for (int i = 0; i < NL_; ++i) {
        const float* WoL   = Wo + (size_t)i * H_ * OD_;
        const float* boLp  = bo + (size_t)i * OD_;
        const float* biasL = bias + (size_t)i * OD_;
        if (i > 0) gemm1_kernel<<<512, 256, 0, stream>>>(cur, Wb, zpart);
        e_kernel<<<256, 256, 0, stream>>>(zpart, bb, base_ready, basef);
        g2_kernel<<<768, 512, 0, stream>>>(base_ready, WoL, biasL, boLp, rx, partial);
        c_kernel<<<256, 256, 0, stream>>>(partial, idxbuf, enc, i);
        d_kernel<<<dim3(32, 12), 256, 0, stream>>>(idxbuf, basef, WoL, boLp, biasL, x, cur, rx);
    }
}